// Round 10
// baseline (1279.885 us; speedup 1.0000x reference)
//
#include <hip/hip_runtime.h>
#include <hip/hip_bf16.h>

#define LEAKY(v) ((v) >= 0.0f ? (v) : 0.01f * (v))

typedef int iv4 __attribute__((ext_vector_type(4)));
typedef unsigned short us4 __attribute__((ext_vector_type(4)));

constexpr int SH = 9;        // rows per bucket = 512
constexpr int RPB = 1 << SH; // 512
constexpr int NBMAX = 320;   // max buckets (n <= 163840)
constexpr int CHUNK = 6144;  // edges per phase-1 block

__device__ __forceinline__ unsigned short f2bf(float v) {
  unsigned u = __float_as_uint(v);
  return (unsigned short)((u + 0x7fffu + ((u >> 16) & 1u)) >> 16);  // RNE
}
__device__ __forceinline__ float bf2f(unsigned short h) {
  return __uint_as_float((unsigned)h << 16);
}

// ---------------------------------------------------------------------------
// k_init: ego -> out cols [0,64) (raw; also serves as layer-0 input).
// ---------------------------------------------------------------------------
__global__ void k_init(const float* __restrict__ ego, float* __restrict__ out, int n) {
  int tid = blockIdx.x * blockDim.x + threadIdx.x;
  int total = n * 16;
  int stride = gridDim.x * blockDim.x;
  for (int t = tid; t < total; t += stride) {
    int r = t >> 4, c = (t & 15) * 4;
    float4 v = *(const float4*)(ego + (size_t)r * 64 + c);
    *(float4*)(out + (size_t)r * 176 + c) = v;
  }
}

// ---------------------------------------------------------------------------
// k_pack: refresh bf16 gather table xh from out cols [src..src+DOUT).
// xh row stride fixed at 64.
// ---------------------------------------------------------------------------
template <int DOUT>
__global__ void k_pack(const float* __restrict__ src, unsigned short* __restrict__ xh,
                       int n) {
  int tid = blockIdx.x * blockDim.x + threadIdx.x;
  constexpr int Q = DOUT / 4;
  int total = n * Q;
  int stride = gridDim.x * blockDim.x;
  for (int t = tid; t < total; t += stride) {
    int r = t / Q, c = (t - r * Q) * 4;
    float4 v = *(const float4*)(src + (size_t)r * 176 + c);
    us4 h;
    h.x = f2bf(v.x); h.y = f2bf(v.y); h.z = f2bf(v.z); h.w = f2bf(v.w);
    *(us4*)(xh + (size_t)r * 64 + c) = h;
  }
}

// ---------------------------------------------------------------------------
// k_hist: bucket (row>>SH) histogram, LDS-staged.
// ---------------------------------------------------------------------------
__global__ void __launch_bounds__(256) k_hist(const int* __restrict__ erow,
                                              int* __restrict__ bcnt, int E, int nb) {
  __shared__ int h[NBMAX];
  for (int i = threadIdx.x; i < NBMAX; i += 256) h[i] = 0;
  __syncthreads();
  int tid = blockIdx.x * blockDim.x + threadIdx.x;
  int stride = gridDim.x * blockDim.x;
  for (int e = tid; e < E; e += stride) atomicAdd(&h[erow[e] >> SH], 1);
  __syncthreads();
  for (int b = threadIdx.x; b < nb; b += 256)
    if (h[b]) atomicAdd(&bcnt[b], h[b]);
}

// ---------------------------------------------------------------------------
// k_scanb: one wave: boff = exclusive scan of bcnt; bcur = boff; rp[n] = E.
// ---------------------------------------------------------------------------
__global__ void k_scanb(const int* __restrict__ bcnt, int* __restrict__ boff,
                        int* __restrict__ bcur, int* __restrict__ rp,
                        int nb, int n, int E) {
  int l = threadIdx.x;  // 64 threads
  constexpr int PB = NBMAX / 64;  // 5
  int local[PB];
  int s = 0;
  int base = l * PB;
  for (int j = 0; j < PB; ++j) {
    int b = base + j;
    int c = (b < nb) ? bcnt[b] : 0;
    local[j] = c;
    s += c;
  }
  int incl = s;
  for (int d = 1; d < 64; d <<= 1) {
    int v = __shfl_up(incl, d);
    if (l >= d) incl += v;
  }
  int ex = incl - s;
  for (int j = 0; j < PB; ++j) {
    int b = base + j;
    if (b <= nb) { boff[b] = ex; bcur[b] = ex; }
    ex += local[j];
  }
  if (l == 63) boff[nb] = incl;
  if (l == 0) rp[n] = E;
}

// ---------------------------------------------------------------------------
// k_bucket (phase 1): LDS counting-sort of a 6144-edge chunk by bucket;
// reserve per-bucket global slices; write bucket-contiguous runs.
// Entry: (localrow<<18 | col, valbits).
// ---------------------------------------------------------------------------
__global__ void __launch_bounds__(256) k_bucket(
    const int* __restrict__ erow, const int* __restrict__ ecol,
    const float* __restrict__ ev, int* __restrict__ bcur,
    int2* __restrict__ bkt, int E, int nb) {
  __shared__ int hist[NBMAX];
  __shared__ int excl[NBMAX + 1];
  __shared__ int curl[NBMAX];
  __shared__ int gbase[NBMAX];
  __shared__ int2 skv[CHUNK];
  int base = blockIdx.x * CHUNK;
  int cnt = min(CHUNK, E - base);

  for (int i = threadIdx.x; i < NBMAX; i += 256) hist[i] = 0;
  __syncthreads();
  for (int i = threadIdx.x; i < cnt; i += 256)
    atomicAdd(&hist[erow[base + i] >> SH], 1);
  __syncthreads();

  if (threadIdx.x < 64) {
    int l = threadIdx.x;
    constexpr int PB = NBMAX / 64;
    int lsum[PB];
    int s = 0;
    for (int j = 0; j < PB; ++j) { lsum[j] = hist[l * PB + j]; s += lsum[j]; }
    int incl = s;
    for (int d = 1; d < 64; d <<= 1) {
      int v = __shfl_up(incl, d);
      if (l >= d) incl += v;
    }
    int ex = incl - s;
    for (int j = 0; j < PB; ++j) { excl[l * PB + j] = ex; ex += lsum[j]; }
    if (l == 63) excl[NBMAX] = incl;
  }
  __syncthreads();

  for (int b = threadIdx.x; b < nb; b += 256) {
    curl[b] = 0;
    int c = hist[b];
    if (c) gbase[b] = atomicAdd(&bcur[b], c);
  }
  __syncthreads();

  for (int i = threadIdx.x; i < cnt; i += 256) {
    int r = erow[base + i];
    int b = r >> SH;
    int lr = r & (RPB - 1);
    int slot = excl[b] + atomicAdd(&curl[b], 1);
    int2 p;
    p.x = (lr << 18) | ecol[base + i];
    p.y = __float_as_int(ev[base + i]);
    skv[slot] = p;
  }
  __syncthreads();

  for (int s = threadIdx.x; s < cnt; s += 256) {
    int lo = 0, hi = nb;
    while (hi - lo > 1) {
      int mid = (lo + hi) >> 1;
      if (excl[mid] <= s) lo = mid; else hi = mid;
    }
    bkt[gbase[lo] + (s - excl[lo])] = skv[s];
  }
}

// ---------------------------------------------------------------------------
// k_bsort (phase 2): one block per bucket; counting-sort by exact local row
// inside the bucket's L2-resident window; write final cv + rp.
// ---------------------------------------------------------------------------
__global__ void __launch_bounds__(512) k_bsort(
    const int* __restrict__ boff, const int2* __restrict__ bkt,
    int2* __restrict__ cv, int* __restrict__ rp, int n) {
  __shared__ int cnt[RPB];
  __shared__ int sc[RPB];
  __shared__ int exs[RPB];
  __shared__ int cur[RPB];
  int b = blockIdx.x;
  int off = boff[b];
  int m = boff[b + 1] - off;
  int t = threadIdx.x;

  cnt[t] = 0;
  __syncthreads();
  for (int i = t; i < m; i += 512) atomicAdd(&cnt[bkt[off + i].x >> 18], 1);
  __syncthreads();
  sc[t] = cnt[t];
  __syncthreads();
  for (int o = 1; o < RPB; o <<= 1) {
    int v = (t >= o) ? sc[t - o] : 0;
    __syncthreads();
    sc[t] += v;
    __syncthreads();
  }
  int ex = sc[t] - cnt[t];
  exs[t] = ex;
  cur[t] = 0;
  int row = (b << SH) + t;
  if (row < n) rp[row] = off + ex;
  __syncthreads();
  for (int i = t; i < m; i += 512) {
    int2 p = bkt[off + i];
    int lr = p.x >> 18;
    int pos = exs[lr] + atomicAdd(&cur[lr], 1);
    int2 q;
    q.x = p.x & 0x3FFFF;
    q.y = p.y;
    cv[off + pos] = q;
  }
}

// ---------------------------------------------------------------------------
// k_layer: fused SpMM (CSR gather from bf16 xh, 128 B/edge) + transform.
// One wave per row; own-row xv stays f32. W1/W2 packed bf16-pair per u32 LDS.
// launch_bounds(256,8) caps VGPRs for occupancy.
// ---------------------------------------------------------------------------
template <int DIN, int DOUT>
__global__ void __launch_bounds__(256, 8) k_layer(
    const int* __restrict__ rp, const int2* __restrict__ cv,
    const unsigned short* __restrict__ xh, const float* xin,
    const float* __restrict__ W1, const float* __restrict__ b1,
    const float* __restrict__ W2, const float* __restrict__ b2,
    float* outp, int n) {
  __shared__ unsigned sWp[DIN * DOUT + 64];
  __shared__ float sb[128];
  for (int i = threadIdx.x; i < DIN * DOUT + 64; i += blockDim.x) {
    float w1 = (i < DIN * DOUT) ? W1[i] : 0.0f;
    float w2 = (i < DIN * DOUT) ? W2[i] : 0.0f;
    unsigned u1 = __float_as_uint(w1), u2 = __float_as_uint(w2);
    unsigned r1 = (u1 + 0x7fffu + ((u1 >> 16) & 1u)) >> 16;
    unsigned r2 = (u2 + 0x7fffu + ((u2 >> 16) & 1u)) & 0xffff0000u;
    sWp[i] = r1 | r2;
  }
  if (threadIdx.x < 64) {
    int i = threadIdx.x;
    sb[i] = (i < DOUT) ? b1[i] : 0.0f;
    sb[64 + i] = (i < DOUT) ? b2[i] : 0.0f;
  }
  __syncthreads();

  int row = (int)((blockIdx.x * (unsigned)blockDim.x + threadIdx.x) >> 6);
  int lane = threadIdx.x & 63;
  if (row >= n) return;

  int f = lane & (DIN - 1);
  int beg = rp[row], end = rp[row + 1];

  float xv = (lane < DIN) ? xin[(size_t)row * 176 + lane] : 0.0f;

  float acc = 0.0f;
  int e = beg;
  if ((e & 1) && e < end) {
    int2 q = cv[e];
    acc = fmaf(__int_as_float(q.y), bf2f(xh[(size_t)q.x * 64 + f]), acc);
    ++e;
  }
  for (; e + 4 <= end; e += 4) {
    iv4 a = *(const iv4*)(cv + e);
    iv4 b = *(const iv4*)(cv + e + 2);
    float g0 = bf2f(xh[(size_t)a.x * 64 + f]);
    float g1 = bf2f(xh[(size_t)a.z * 64 + f]);
    float g2 = bf2f(xh[(size_t)b.x * 64 + f]);
    float g3 = bf2f(xh[(size_t)b.z * 64 + f]);
    acc = fmaf(__int_as_float(a.y), g0, acc);
    acc = fmaf(__int_as_float(a.w), g1, acc);
    acc = fmaf(__int_as_float(b.y), g2, acc);
    acc = fmaf(__int_as_float(b.w), g3, acc);
  }
  for (; e + 2 <= end; e += 2) {
    iv4 a = *(const iv4*)(cv + e);
    float g0 = bf2f(xh[(size_t)a.x * 64 + f]);
    float g1 = bf2f(xh[(size_t)a.z * 64 + f]);
    acc = fmaf(__int_as_float(a.y), g0, acc);
    acc = fmaf(__int_as_float(a.w), g1, acc);
  }
  if (e < end) {
    int2 q = cv[e];
    acc = fmaf(__int_as_float(q.y), bf2f(xh[(size_t)q.x * 64 + f]), acc);
  }

  float a_ = xv + acc;
  float m_ = xv * acc;

  float acc1 = sb[lane], acc2 = sb[64 + lane];
#pragma unroll 8
  for (int k = 0; k < DIN; ++k) {
    float ak = __shfl(a_, k), mk = __shfl(m_, k);
    unsigned w = sWp[k * DOUT + lane];
    acc1 = fmaf(ak, __uint_as_float(w << 16), acc1);
    acc2 = fmaf(mk, __uint_as_float(w & 0xffff0000u), acc2);
  }
  float xn = LEAKY(acc1) + LEAKY(acc2);
  if (lane < DOUT) outp[(size_t)row * 176 + lane] = xn;
}

// ---------------------------------------------------------------------------
// k_norm: L2-normalize cols [64,128), [128,160), [160,176) in place.
// ---------------------------------------------------------------------------
__global__ void __launch_bounds__(256) k_norm(float* out, int n) {
  int row = (int)((blockIdx.x * (unsigned)blockDim.x + threadIdx.x) >> 6);
  int lane = threadIdx.x & 63;
  if (row >= n) return;
  float* r = out + (size_t)row * 176;
  float a = r[64 + lane];
  float b = (lane < 48) ? r[128 + lane] : 0.0f;
  float sa = a * a;
  float sb_ = (lane < 32) ? b * b : 0.0f;
  float sc = (lane >= 32 && lane < 48) ? b * b : 0.0f;
#pragma unroll
  for (int off = 32; off; off >>= 1) {
    sa += __shfl_xor(sa, off);
    sb_ += __shfl_xor(sb_, off);
    sc += __shfl_xor(sc, off);
  }
  float ia = 1.0f / fmaxf(sqrtf(sa), 1e-12f);
  float ib = 1.0f / fmaxf(sqrtf(sb_), 1e-12f);
  float ic = 1.0f / fmaxf(sqrtf(sc), 1e-12f);
  r[64 + lane] = a * ia;
  if (lane < 48) r[128 + lane] = b * ((lane < 32) ? ib : ic);
}

// ---------------------------------------------------------------------------
extern "C" void kernel_launch(void* const* d_in, const int* in_sizes, int n_in,
                              void* d_out, int out_size, void* d_ws, size_t ws_size,
                              hipStream_t stream) {
  const float* ego = (const float*)d_in[0];
  const int* erow = (const int*)d_in[1];
  const int* ecol = (const int*)d_in[2];
  const float* ev = (const float*)d_in[3];
  const int n = in_sizes[0] / 64;  // 160000
  const int E = in_sizes[1];       // 5120000
  const int nb = (n + RPB - 1) >> SH;  // 313

  float* out = (float*)d_out;  // [n, 176] f32

  // ws: bkt[E] | cv[E] | rp[n+1] | bcnt | boff | bcur   (~82.7 MB, proven)
  // xh (bf16 gather table, 20.5 MB) OVERLAYS bkt — bkt is dead after k_bsort.
  int2* bkt = (int2*)d_ws;
  int2* cv = bkt + E;
  int* rp = (int*)(cv + E);
  int* bcnt = rp + n + 1;
  int* boff = bcnt + NBMAX;
  int* bcur = boff + NBMAX + 1;
  unsigned short* xh = (unsigned short*)d_ws;

  const int rblocks = (n + 3) / 4;  // one wave per row, 4 waves/block

  k_init<<<2048, 256, 0, stream>>>(ego, out, n);
  hipMemsetAsync(bcnt, 0, NBMAX * sizeof(int), stream);
  k_hist<<<1024, 256, 0, stream>>>(erow, bcnt, E, nb);
  k_scanb<<<1, 64, 0, stream>>>(bcnt, boff, bcur, rp, nb, n, E);
  k_bucket<<<(E + CHUNK - 1) / CHUNK, 256, 0, stream>>>(erow, ecol, ev, bcur, bkt, E, nb);
  k_bsort<<<nb, 512, 0, stream>>>(boff, bkt, cv, rp, n);

  // bkt dead from here; xh takes its space
  k_pack<64><<<1024, 256, 0, stream>>>(out, xh, n);
  k_layer<64, 64><<<rblocks, 256, 0, stream>>>(
      rp, cv, xh, out, (const float*)d_in[4], (const float*)d_in[5],
      (const float*)d_in[6], (const float*)d_in[7], out + 64, n);
  k_pack<64><<<1024, 256, 0, stream>>>(out + 64, xh, n);
  k_layer<64, 32><<<rblocks, 256, 0, stream>>>(
      rp, cv, xh, out + 64, (const float*)d_in[8], (const float*)d_in[9],
      (const float*)d_in[10], (const float*)d_in[11], out + 128, n);
  k_pack<32><<<1024, 256, 0, stream>>>(out + 128, xh, n);
  k_layer<32, 16><<<rblocks, 256, 0, stream>>>(
      rp, cv, xh, out + 128, (const float*)d_in[12], (const float*)d_in[13],
      (const float*)d_in[14], (const float*)d_in[15], out + 160, n);

  k_norm<<<rblocks, 256, 0, stream>>>(out, n);
}

// Round 11
// 860.821 us; speedup vs baseline: 1.4868x; 1.4868x over previous
//
#include <hip/hip_runtime.h>
#include <hip/hip_bf16.h>

#define LEAKY(v) ((v) >= 0.0f ? (v) : 0.01f * (v))

typedef int iv4 __attribute__((ext_vector_type(4)));
typedef unsigned short us4 __attribute__((ext_vector_type(4)));
typedef short s8v __attribute__((ext_vector_type(8)));   // 8 bf16 (4 VGPRs)
typedef float f4 __attribute__((ext_vector_type(4)));    // MFMA acc

constexpr int SH = 9;        // rows per bucket = 512
constexpr int RPB = 1 << SH; // 512
constexpr int NBMAX = 320;   // max buckets (n <= 163840)
constexpr int CHUNK = 6144;  // edges per phase-1 block

__device__ __forceinline__ unsigned short f2bf(float v) {
  unsigned u = __float_as_uint(v);
  return (unsigned short)((u + 0x7fffu + ((u >> 16) & 1u)) >> 16);  // RNE
}
__device__ __forceinline__ float bf2f(unsigned short h) {
  return __uint_as_float((unsigned)h << 16);
}

// ---------------------------------------------------------------------------
// k_init: ego -> out cols [0,64); optionally also bf16 gather table xh.
// ---------------------------------------------------------------------------
__global__ void k_init(const float* __restrict__ ego, float* __restrict__ out,
                       unsigned short* __restrict__ xh, int n) {
  int tid = blockIdx.x * blockDim.x + threadIdx.x;
  int total = n * 16;
  int stride = gridDim.x * blockDim.x;
  for (int t = tid; t < total; t += stride) {
    int r = t >> 4, c = (t & 15) * 4;
    float4 v = *(const float4*)(ego + (size_t)r * 64 + c);
    *(float4*)(out + (size_t)r * 176 + c) = v;
    if (xh) {
      us4 h;
      h.x = f2bf(v.x); h.y = f2bf(v.y); h.z = f2bf(v.z); h.w = f2bf(v.w);
      *(us4*)(xh + (size_t)r * 64 + c) = h;
    }
  }
}

// ---------------------------------------------------------------------------
// Sort pipeline (proven round 9): hist -> scanb -> bucket -> bsort
// ---------------------------------------------------------------------------
__global__ void __launch_bounds__(256) k_hist(const int* __restrict__ erow,
                                              int* __restrict__ bcnt, int E, int nb) {
  __shared__ int h[NBMAX];
  for (int i = threadIdx.x; i < NBMAX; i += 256) h[i] = 0;
  __syncthreads();
  int tid = blockIdx.x * blockDim.x + threadIdx.x;
  int stride = gridDim.x * blockDim.x;
  for (int e = tid; e < E; e += stride) atomicAdd(&h[erow[e] >> SH], 1);
  __syncthreads();
  for (int b = threadIdx.x; b < nb; b += 256)
    if (h[b]) atomicAdd(&bcnt[b], h[b]);
}

__global__ void k_scanb(const int* __restrict__ bcnt, int* __restrict__ boff,
                        int* __restrict__ bcur, int* __restrict__ rp,
                        int nb, int n, int E) {
  int l = threadIdx.x;  // 64 threads
  constexpr int PB = NBMAX / 64;
  int local[PB];
  int s = 0;
  int base = l * PB;
  for (int j = 0; j < PB; ++j) {
    int b = base + j;
    int c = (b < nb) ? bcnt[b] : 0;
    local[j] = c;
    s += c;
  }
  int incl = s;
  for (int d = 1; d < 64; d <<= 1) {
    int v = __shfl_up(incl, d);
    if (l >= d) incl += v;
  }
  int ex = incl - s;
  for (int j = 0; j < PB; ++j) {
    int b = base + j;
    if (b <= nb) { boff[b] = ex; bcur[b] = ex; }
    ex += local[j];
  }
  if (l == 63) boff[nb] = incl;
  if (l == 0) rp[n] = E;
}

__global__ void __launch_bounds__(256) k_bucket(
    const int* __restrict__ erow, const int* __restrict__ ecol,
    const float* __restrict__ ev, int* __restrict__ bcur,
    int2* __restrict__ bkt, int E, int nb) {
  __shared__ int hist[NBMAX];
  __shared__ int excl[NBMAX + 1];
  __shared__ int curl[NBMAX];
  __shared__ int gbase[NBMAX];
  __shared__ int2 skv[CHUNK];
  int base = blockIdx.x * CHUNK;
  int cnt = min(CHUNK, E - base);

  for (int i = threadIdx.x; i < NBMAX; i += 256) hist[i] = 0;
  __syncthreads();
  for (int i = threadIdx.x; i < cnt; i += 256)
    atomicAdd(&hist[erow[base + i] >> SH], 1);
  __syncthreads();

  if (threadIdx.x < 64) {
    int l = threadIdx.x;
    constexpr int PB = NBMAX / 64;
    int lsum[PB];
    int s = 0;
    for (int j = 0; j < PB; ++j) { lsum[j] = hist[l * PB + j]; s += lsum[j]; }
    int incl = s;
    for (int d = 1; d < 64; d <<= 1) {
      int v = __shfl_up(incl, d);
      if (l >= d) incl += v;
    }
    int ex = incl - s;
    for (int j = 0; j < PB; ++j) { excl[l * PB + j] = ex; ex += lsum[j]; }
    if (l == 63) excl[NBMAX] = incl;
  }
  __syncthreads();

  for (int b = threadIdx.x; b < nb; b += 256) {
    curl[b] = 0;
    int c = hist[b];
    if (c) gbase[b] = atomicAdd(&bcur[b], c);
  }
  __syncthreads();

  for (int i = threadIdx.x; i < cnt; i += 256) {
    int r = erow[base + i];
    int b = r >> SH;
    int lr = r & (RPB - 1);
    int slot = excl[b] + atomicAdd(&curl[b], 1);
    int2 p;
    p.x = (lr << 18) | ecol[base + i];
    p.y = __float_as_int(ev[base + i]);
    skv[slot] = p;
  }
  __syncthreads();

  for (int s = threadIdx.x; s < cnt; s += 256) {
    int lo = 0, hi = nb;
    while (hi - lo > 1) {
      int mid = (lo + hi) >> 1;
      if (excl[mid] <= s) lo = mid; else hi = mid;
    }
    bkt[gbase[lo] + (s - excl[lo])] = skv[s];
  }
}

__global__ void __launch_bounds__(512) k_bsort(
    const int* __restrict__ boff, const int2* __restrict__ bkt,
    int2* __restrict__ cv, int* __restrict__ rp, int n) {
  __shared__ int cnt[RPB];
  __shared__ int sc[RPB];
  __shared__ int exs[RPB];
  __shared__ int cur[RPB];
  int b = blockIdx.x;
  int off = boff[b];
  int m = boff[b + 1] - off;
  int t = threadIdx.x;

  cnt[t] = 0;
  __syncthreads();
  for (int i = t; i < m; i += 512) atomicAdd(&cnt[bkt[off + i].x >> 18], 1);
  __syncthreads();
  sc[t] = cnt[t];
  __syncthreads();
  for (int o = 1; o < RPB; o <<= 1) {
    int v = (t >= o) ? sc[t - o] : 0;
    __syncthreads();
    sc[t] += v;
    __syncthreads();
  }
  int ex = sc[t] - cnt[t];
  exs[t] = ex;
  cur[t] = 0;
  int row = (b << SH) + t;
  if (row < n) rp[row] = off + ex;
  __syncthreads();
  for (int i = t; i < m; i += 512) {
    int2 p = bkt[off + i];
    int lr = p.x >> 18;
    int pos = exs[lr] + atomicAdd(&cur[lr], 1);
    int2 q;
    q.x = p.x & 0x3FFFF;
    q.y = p.y;
    cv[off + pos] = q;
  }
}

// ---------------------------------------------------------------------------
// k_gam: gather-only SpMM. One wave per row, lane = feature.
// side = sum val_e * x[col_e];  a = x+side, m = x*side
// amp[row][lane] = bf16(a) | bf16(m)<<16.
// BF: gather from bf16 table xh (stride 64); else f32 from xin (stride 176).
// ---------------------------------------------------------------------------
template <int DIN, bool BF>
__global__ void __launch_bounds__(256, 8) k_gam(
    const int* __restrict__ rp, const int2* __restrict__ cv,
    const unsigned short* __restrict__ xh, const float* __restrict__ xin,
    unsigned* __restrict__ amp, int n) {
  int row = (int)((blockIdx.x * (unsigned)blockDim.x + threadIdx.x) >> 6);
  int lane = threadIdx.x & 63;
  if (row >= n) return;

  int f = lane & (DIN - 1);
  int beg = rp[row], end = rp[row + 1];

  float xv = (lane < DIN) ? xin[(size_t)row * 176 + lane] : 0.0f;

#define GATH(col) (BF ? bf2f(xh[(unsigned)((col) * 64 + f)]) \
                      : xin[(size_t)(col) * 176 + f])
  float acc = 0.0f;
  int e = beg;
  if ((e & 1) && e < end) {
    int2 q = cv[e];
    acc = fmaf(__int_as_float(q.y), GATH(q.x), acc);
    ++e;
  }
  for (; e + 4 <= end; e += 4) {
    iv4 a = *(const iv4*)(cv + e);
    iv4 b = *(const iv4*)(cv + e + 2);
    float g0 = GATH(a.x);
    float g1 = GATH(a.z);
    float g2 = GATH(b.x);
    float g3 = GATH(b.z);
    acc = fmaf(__int_as_float(a.y), g0, acc);
    acc = fmaf(__int_as_float(a.w), g1, acc);
    acc = fmaf(__int_as_float(b.y), g2, acc);
    acc = fmaf(__int_as_float(b.w), g3, acc);
  }
  for (; e + 2 <= end; e += 2) {
    iv4 a = *(const iv4*)(cv + e);
    float g0 = GATH(a.x);
    float g1 = GATH(a.z);
    acc = fmaf(__int_as_float(a.y), g0, acc);
    acc = fmaf(__int_as_float(a.w), g1, acc);
  }
  if (e < end) {
    int2 q = cv[e];
    acc = fmaf(__int_as_float(q.y), GATH(q.x), acc);
  }
#undef GATH

  if (lane < DIN) {
    float a = xv + acc, m = xv * acc;
    amp[(size_t)row * 64 + lane] = (unsigned)f2bf(a) | ((unsigned)f2bf(m) << 16);
  }
}

// ---------------------------------------------------------------------------
// k_xf: MFMA transform. Block = 64 rows, 4 waves; wave w owns rows w*16..+16.
//   xn = leaky(A@W1 + b1) + leaky(M@W2 + b2)
// A/M and transposed W1/W2 staged in XOR-swizzled LDS (T2: row-stride>=64B
// would otherwise bank-conflict on ds_read_b128).
// Writes f32 out (+ bf16 gather table xh for the next layer, if non-null).
// ---------------------------------------------------------------------------
template <int DIN, int DOUT>
__global__ void __launch_bounds__(256) k_xf(
    const unsigned* __restrict__ amp,
    const float* __restrict__ W1, const float* __restrict__ b1,
    const float* __restrict__ W2, const float* __restrict__ b2,
    float* __restrict__ outp, unsigned short* __restrict__ xh, int n) {
  constexpr int ROWB = DIN * 2;          // LDS row stride (bytes)
  constexpr int RMASK = (ROWB / 16) - 1; // swizzle mask
  constexpr int NTC = DOUT / 16;
  __shared__ unsigned short sA[64 * DIN];
  __shared__ unsigned short sM[64 * DIN];
  __shared__ unsigned short sW1[DOUT * DIN];
  __shared__ unsigned short sW2[DOUT * DIN];

  int row0 = blockIdx.x * 64;

  // stage A/M (pairs of features -> one dword store each)
  constexpr int PAIRS = DIN / 2;
  for (int i = threadIdx.x; i < 64 * PAIRS; i += 256) {
    int r = i / PAIRS, fp = (i - r * PAIRS) * 2;
    unsigned lo = 0, hi = 0;
    if (row0 + r < n) {
      uint2 q = *(const uint2*)(amp + (size_t)(row0 + r) * 64 + fp);
      lo = (q.x & 0xffffu) | ((q.y & 0xffffu) << 16);  // a pair
      hi = (q.x >> 16) | (q.y & 0xffff0000u);          // m pair
    }
    int boff = r * ROWB + ((fp * 2) ^ ((r & RMASK) << 4));
    *(unsigned*)((char*)sA + boff) = lo;
    *(unsigned*)((char*)sM + boff) = hi;
  }
  // stage W^T (bf16), row = out col c, contiguous in k
  for (int i = threadIdx.x; i < DIN * DOUT; i += 256) {
    int k = i / DOUT, c = i - k * DOUT;
    int boff = c * ROWB + ((k * 2) ^ ((c & RMASK) << 4));
    *(unsigned short*)((char*)sW1 + boff) = f2bf(W1[i]);
    *(unsigned short*)((char*)sW2 + boff) = f2bf(W2[i]);
  }
  __syncthreads();

  int w = threadIdx.x >> 6, l = threadIdx.x & 63;
  int tr = w;  // 16-row group

  f4 acc1[NTC], acc2[NTC];
#pragma unroll
  for (int tc = 0; tc < NTC; ++tc) {
    acc1[tc] = (f4){0.0f, 0.0f, 0.0f, 0.0f};
    acc2[tc] = (f4){0.0f, 0.0f, 0.0f, 0.0f};
  }

#pragma unroll
  for (int k0 = 0; k0 < DIN; k0 += 32) {
    int ra = tr * 16 + (l & 15);
    int inb = (k0 + (l >> 4) * 8) * 2;
    s8v af = *(const s8v*)((const char*)sA + ra * ROWB + (inb ^ ((ra & RMASK) << 4)));
    s8v mf = *(const s8v*)((const char*)sM + ra * ROWB + (inb ^ ((ra & RMASK) << 4)));
#pragma unroll
    for (int tc = 0; tc < NTC; ++tc) {
      int rc = tc * 16 + (l & 15);
      int wb = rc * ROWB + (inb ^ ((rc & RMASK) << 4));
      s8v w1 = *(const s8v*)((const char*)sW1 + wb);
      s8v w2 = *(const s8v*)((const char*)sW2 + wb);
      acc1[tc] = __builtin_amdgcn_mfma_f32_16x16x32_bf16(af, w1, acc1[tc], 0, 0, 0);
      acc2[tc] = __builtin_amdgcn_mfma_f32_16x16x32_bf16(mf, w2, acc2[tc], 0, 0, 0);
    }
  }

  // epilogue: C/D layout col=lane&15, row=(lane>>4)*4+reg  [m89-verified]
#pragma unroll
  for (int tc = 0; tc < NTC; ++tc) {
    int c = tc * 16 + (l & 15);
    float bb1 = b1[c], bb2 = b2[c];
#pragma unroll
    for (int j = 0; j < 4; ++j) {
      int r = tr * 16 + (l >> 4) * 4 + j;
      if (row0 + r < n) {
        float v1 = acc1[tc][j] + bb1;
        float v2 = acc2[tc][j] + bb2;
        float xn = LEAKY(v1) + LEAKY(v2);
        outp[(size_t)(row0 + r) * 176 + c] = xn;
        if (xh) xh[(size_t)(row0 + r) * 64 + c] = f2bf(xn);
      }
    }
  }
}

// ---------------------------------------------------------------------------
// k_norm: L2-normalize cols [64,128), [128,160), [160,176) in place.
// ---------------------------------------------------------------------------
__global__ void __launch_bounds__(256) k_norm(float* out, int n) {
  int row = (int)((blockIdx.x * (unsigned)blockDim.x + threadIdx.x) >> 6);
  int lane = threadIdx.x & 63;
  if (row >= n) return;
  float* r = out + (size_t)row * 176;
  float a = r[64 + lane];
  float b = (lane < 48) ? r[128 + lane] : 0.0f;
  float sa = a * a;
  float sb_ = (lane < 32) ? b * b : 0.0f;
  float sc = (lane >= 32 && lane < 48) ? b * b : 0.0f;
#pragma unroll
  for (int off = 32; off; off >>= 1) {
    sa += __shfl_xor(sa, off);
    sb_ += __shfl_xor(sb_, off);
    sc += __shfl_xor(sc, off);
  }
  float ia = 1.0f / fmaxf(sqrtf(sa), 1e-12f);
  float ib = 1.0f / fmaxf(sqrtf(sb_), 1e-12f);
  float ic = 1.0f / fmaxf(sqrtf(sc), 1e-12f);
  r[64 + lane] = a * ia;
  if (lane < 48) r[128 + lane] = b * ((lane < 32) ? ib : ic);
}

// ---------------------------------------------------------------------------
extern "C" void kernel_launch(void* const* d_in, const int* in_sizes, int n_in,
                              void* d_out, int out_size, void* d_ws, size_t ws_size,
                              hipStream_t stream) {
  const float* ego = (const float*)d_in[0];
  const int* erow = (const int*)d_in[1];
  const int* ecol = (const int*)d_in[2];
  const float* ev = (const float*)d_in[3];
  const int n = in_sizes[0] / 64;  // 160000
  const int E = in_sizes[1];       // 5120000
  const int nb = (n + RPB - 1) >> SH;

  float* out = (float*)d_out;  // [n, 176] f32

  // ws: bkt[E] (amp overlays) | cv[E] | rp[n+1] | meta | [xh if room]
  int2* bkt = (int2*)d_ws;
  int2* cv = bkt + E;
  int* rp = (int*)(cv + E);
  int* bcnt = rp + n + 1;
  int* boff = bcnt + NBMAX;
  int* bcur = boff + NBMAX + 1;
  unsigned short* xh = (unsigned short*)(bcur + NBMAX);
  unsigned* amp = (unsigned*)d_ws;  // overlays bkt (dead after k_bsort)

  size_t need_bf = (size_t)((char*)(xh + (size_t)n * 64) - (char*)d_ws);
  bool bf = ws_size >= need_bf;
  unsigned short* xhp = bf ? xh : nullptr;

  const int rblocks = (n + 3) / 4;   // k_gam: one wave per row
  const int xblocks = (n + 63) / 64; // k_xf: 64 rows per block

  k_init<<<2048, 256, 0, stream>>>(ego, out, xhp, n);
  hipMemsetAsync(bcnt, 0, NBMAX * sizeof(int), stream);
  k_hist<<<1024, 256, 0, stream>>>(erow, bcnt, E, nb);
  k_scanb<<<1, 64, 0, stream>>>(bcnt, boff, bcur, rp, nb, n, E);
  k_bucket<<<(E + CHUNK - 1) / CHUNK, 256, 0, stream>>>(erow, ecol, ev, bcur, bkt, E, nb);
  k_bsort<<<nb, 512, 0, stream>>>(boff, bkt, cv, rp, n);
  // bkt dead from here; amp takes its space

  const float* W1_0 = (const float*)d_in[4];
  const float* B1_0 = (const float*)d_in[5];
  const float* W2_0 = (const float*)d_in[6];
  const float* B2_0 = (const float*)d_in[7];
  const float* W1_1 = (const float*)d_in[8];
  const float* B1_1 = (const float*)d_in[9];
  const float* W2_1 = (const float*)d_in[10];
  const float* B2_1 = (const float*)d_in[11];
  const float* W1_2 = (const float*)d_in[12];
  const float* B1_2 = (const float*)d_in[13];
  const float* W2_2 = (const float*)d_in[14];
  const float* B2_2 = (const float*)d_in[15];

  if (bf) {
    k_gam<64, true><<<rblocks, 256, 0, stream>>>(rp, cv, xh, out, amp, n);
    k_xf<64, 64><<<xblocks, 256, 0, stream>>>(amp, W1_0, B1_0, W2_0, B2_0, out + 64, xh, n);
    k_gam<64, true><<<rblocks, 256, 0, stream>>>(rp, cv, xh, out + 64, amp, n);
    k_xf<64, 32><<<xblocks, 256, 0, stream>>>(amp, W1_1, B1_1, W2_1, B2_1, out + 128, xh, n);
    k_gam<32, true><<<rblocks, 256, 0, stream>>>(rp, cv, xh, out + 128, amp, n);
    k_xf<32, 16><<<xblocks, 256, 0, stream>>>(amp, W1_2, B1_2, W2_2, B2_2, out + 160, nullptr, n);
  } else {
    k_gam<64, false><<<rblocks, 256, 0, stream>>>(rp, cv, nullptr, out, amp, n);
    k_xf<64, 64><<<xblocks, 256, 0, stream>>>(amp, W1_0, B1_0, W2_0, B2_0, out + 64, nullptr, n);
    k_gam<64, false><<<rblocks, 256, 0, stream>>>(rp, cv, nullptr, out + 64, amp, n);
    k_xf<64, 32><<<xblocks, 256, 0, stream>>>(amp, W1_1, B1_1, W2_1, B2_1, out + 128, nullptr, n);
    k_gam<32, false><<<rblocks, 256, 0, stream>>>(rp, cv, nullptr, out + 128, amp, n);
    k_xf<32, 16><<<xblocks, 256, 0, stream>>>(amp, W1_2, B1_2, W2_2, B2_2, out + 160, nullptr, n);
  }

  k_norm<<<rblocks, 256, 0, stream>>>(out, n);
}

// Round 12
// 804.813 us; speedup vs baseline: 1.5903x; 1.0696x over previous
//
#include <hip/hip_runtime.h>
#include <hip/hip_bf16.h>

#define LEAKY(v) ((v) >= 0.0f ? (v) : 0.01f * (v))

typedef int iv4 __attribute__((ext_vector_type(4)));
typedef unsigned short us4 __attribute__((ext_vector_type(4)));
typedef short s8v __attribute__((ext_vector_type(8)));   // 8 bf16 (4 VGPRs)
typedef float f4 __attribute__((ext_vector_type(4)));    // MFMA acc

constexpr int SH = 9;        // rows per bucket = 512
constexpr int RPB = 1 << SH; // 512
constexpr int NBMAX = 320;   // max buckets (n <= 163840)
constexpr int CHUNK = 6144;  // edges per phase-1 block

__device__ __forceinline__ unsigned short f2bf(float v) {
  unsigned u = __float_as_uint(v);
  return (unsigned short)((u + 0x7fffu + ((u >> 16) & 1u)) >> 16);  // RNE
}
__device__ __forceinline__ float bf2f(unsigned short h) {
  return __uint_as_float((unsigned)h << 16);
}

// ---------------------------------------------------------------------------
// k_init: ego -> out cols [0,64); optionally also bf16 gather table xh.
// ---------------------------------------------------------------------------
__global__ void k_init(const float* __restrict__ ego, float* __restrict__ out,
                       unsigned short* __restrict__ xh, int n) {
  int tid = blockIdx.x * blockDim.x + threadIdx.x;
  int total = n * 16;
  int stride = gridDim.x * blockDim.x;
  for (int t = tid; t < total; t += stride) {
    int r = t >> 4, c = (t & 15) * 4;
    float4 v = *(const float4*)(ego + (size_t)r * 64 + c);
    *(float4*)(out + (size_t)r * 176 + c) = v;
    if (xh) {
      us4 h;
      h.x = f2bf(v.x); h.y = f2bf(v.y); h.z = f2bf(v.z); h.w = f2bf(v.w);
      *(us4*)(xh + (size_t)r * 64 + c) = h;
    }
  }
}

// ---------------------------------------------------------------------------
// Sort pipeline (proven round 9): hist -> scanb -> bucket -> bsort
// ---------------------------------------------------------------------------
__global__ void __launch_bounds__(256) k_hist(const int* __restrict__ erow,
                                              int* __restrict__ bcnt, int E, int nb) {
  __shared__ int h[NBMAX];
  for (int i = threadIdx.x; i < NBMAX; i += 256) h[i] = 0;
  __syncthreads();
  int tid = blockIdx.x * blockDim.x + threadIdx.x;
  int stride = gridDim.x * blockDim.x;
  for (int e = tid; e < E; e += stride) atomicAdd(&h[erow[e] >> SH], 1);
  __syncthreads();
  for (int b = threadIdx.x; b < nb; b += 256)
    if (h[b]) atomicAdd(&bcnt[b], h[b]);
}

__global__ void k_scanb(const int* __restrict__ bcnt, int* __restrict__ boff,
                        int* __restrict__ bcur, int* __restrict__ rp,
                        int nb, int n, int E) {
  int l = threadIdx.x;  // 64 threads
  constexpr int PB = NBMAX / 64;
  int local[PB];
  int s = 0;
  int base = l * PB;
  for (int j = 0; j < PB; ++j) {
    int b = base + j;
    int c = (b < nb) ? bcnt[b] : 0;
    local[j] = c;
    s += c;
  }
  int incl = s;
  for (int d = 1; d < 64; d <<= 1) {
    int v = __shfl_up(incl, d);
    if (l >= d) incl += v;
  }
  int ex = incl - s;
  for (int j = 0; j < PB; ++j) {
    int b = base + j;
    if (b <= nb) { boff[b] = ex; bcur[b] = ex; }
    ex += local[j];
  }
  if (l == 63) boff[nb] = incl;
  if (l == 0) rp[n] = E;
}

__global__ void __launch_bounds__(256) k_bucket(
    const int* __restrict__ erow, const int* __restrict__ ecol,
    const float* __restrict__ ev, int* __restrict__ bcur,
    int2* __restrict__ bkt, int E, int nb) {
  __shared__ int hist[NBMAX];
  __shared__ int excl[NBMAX + 1];
  __shared__ int curl[NBMAX];
  __shared__ int gbase[NBMAX];
  __shared__ int2 skv[CHUNK];
  int base = blockIdx.x * CHUNK;
  int cnt = min(CHUNK, E - base);

  for (int i = threadIdx.x; i < NBMAX; i += 256) hist[i] = 0;
  __syncthreads();
  for (int i = threadIdx.x; i < cnt; i += 256)
    atomicAdd(&hist[erow[base + i] >> SH], 1);
  __syncthreads();

  if (threadIdx.x < 64) {
    int l = threadIdx.x;
    constexpr int PB = NBMAX / 64;
    int lsum[PB];
    int s = 0;
    for (int j = 0; j < PB; ++j) { lsum[j] = hist[l * PB + j]; s += lsum[j]; }
    int incl = s;
    for (int d = 1; d < 64; d <<= 1) {
      int v = __shfl_up(incl, d);
      if (l >= d) incl += v;
    }
    int ex = incl - s;
    for (int j = 0; j < PB; ++j) { excl[l * PB + j] = ex; ex += lsum[j]; }
    if (l == 63) excl[NBMAX] = incl;
  }
  __syncthreads();

  for (int b = threadIdx.x; b < nb; b += 256) {
    curl[b] = 0;
    int c = hist[b];
    if (c) gbase[b] = atomicAdd(&bcur[b], c);
  }
  __syncthreads();

  for (int i = threadIdx.x; i < cnt; i += 256) {
    int r = erow[base + i];
    int b = r >> SH;
    int lr = r & (RPB - 1);
    int slot = excl[b] + atomicAdd(&curl[b], 1);
    int2 p;
    p.x = (lr << 18) | ecol[base + i];
    p.y = __float_as_int(ev[base + i]);
    skv[slot] = p;
  }
  __syncthreads();

  for (int s = threadIdx.x; s < cnt; s += 256) {
    int lo = 0, hi = nb;
    while (hi - lo > 1) {
      int mid = (lo + hi) >> 1;
      if (excl[mid] <= s) lo = mid; else hi = mid;
    }
    bkt[gbase[lo] + (s - excl[lo])] = skv[s];
  }
}

__global__ void __launch_bounds__(512) k_bsort(
    const int* __restrict__ boff, const int2* __restrict__ bkt,
    int2* __restrict__ cv, int* __restrict__ rp, int n) {
  __shared__ int cnt[RPB];
  __shared__ int sc[RPB];
  __shared__ int exs[RPB];
  __shared__ int cur[RPB];
  int b = blockIdx.x;
  int off = boff[b];
  int m = boff[b + 1] - off;
  int t = threadIdx.x;

  cnt[t] = 0;
  __syncthreads();
  for (int i = t; i < m; i += 512) atomicAdd(&cnt[bkt[off + i].x >> 18], 1);
  __syncthreads();
  sc[t] = cnt[t];
  __syncthreads();
  for (int o = 1; o < RPB; o <<= 1) {
    int v = (t >= o) ? sc[t - o] : 0;
    __syncthreads();
    sc[t] += v;
    __syncthreads();
  }
  int ex = sc[t] - cnt[t];
  exs[t] = ex;
  cur[t] = 0;
  int row = (b << SH) + t;
  if (row < n) rp[row] = off + ex;
  __syncthreads();
  for (int i = t; i < m; i += 512) {
    int2 p = bkt[off + i];
    int lr = p.x >> 18;
    int pos = exs[lr] + atomicAdd(&cur[lr], 1);
    int2 q;
    q.x = p.x & 0x3FFFF;
    q.y = p.y;
    cv[off + pos] = q;
  }
}

// ---------------------------------------------------------------------------
// k_gam: gather-only SpMM. DIN=64: one wave/row, 8 gathers in flight.
// DIN=32: half-wave edge-parallel (each half owns alternate edges), then
// cross-half reduce. amp[row][f] = bf16(a) | bf16(m)<<16.
// BF: gather from bf16 table xh (stride 64); else f32 from xin (stride 176).
// ---------------------------------------------------------------------------
template <int DIN, bool BF>
__global__ void __launch_bounds__(256, 8) k_gam(
    const int* __restrict__ rp, const int2* __restrict__ cv,
    const unsigned short* __restrict__ xh, const float* __restrict__ xin,
    unsigned* __restrict__ amp, int n) {
  int row = (int)((blockIdx.x * (unsigned)blockDim.x + threadIdx.x) >> 6);
  int lane = threadIdx.x & 63;
  if (row >= n) return;

  int beg = rp[row], end = rp[row + 1];

  if constexpr (DIN == 64) {
    int f = lane;
    float xv = xin[(size_t)row * 176 + f];
#define GATH(col) (BF ? bf2f(xh[(size_t)(unsigned)(col) * 64 + f]) \
                      : xin[(size_t)(unsigned)(col) * 176 + f])
    float acc = 0.0f;
    int e = beg;
    if ((e & 1) && e < end) {
      int2 q = cv[e];
      acc = fmaf(__int_as_float(q.y), GATH(q.x), acc);
      ++e;
    }
    for (; e + 8 <= end; e += 8) {
      iv4 a = *(const iv4*)(cv + e);
      iv4 b = *(const iv4*)(cv + e + 2);
      iv4 c = *(const iv4*)(cv + e + 4);
      iv4 d = *(const iv4*)(cv + e + 6);
      float g0 = GATH(a.x);
      float g1 = GATH(a.z);
      float g2 = GATH(b.x);
      float g3 = GATH(b.z);
      float g4 = GATH(c.x);
      float g5 = GATH(c.z);
      float g6 = GATH(d.x);
      float g7 = GATH(d.z);
      acc = fmaf(__int_as_float(a.y), g0, acc);
      acc = fmaf(__int_as_float(a.w), g1, acc);
      acc = fmaf(__int_as_float(b.y), g2, acc);
      acc = fmaf(__int_as_float(b.w), g3, acc);
      acc = fmaf(__int_as_float(c.y), g4, acc);
      acc = fmaf(__int_as_float(c.w), g5, acc);
      acc = fmaf(__int_as_float(d.y), g6, acc);
      acc = fmaf(__int_as_float(d.w), g7, acc);
    }
    for (; e + 2 <= end; e += 2) {
      iv4 a = *(const iv4*)(cv + e);
      float g0 = GATH(a.x);
      float g1 = GATH(a.z);
      acc = fmaf(__int_as_float(a.y), g0, acc);
      acc = fmaf(__int_as_float(a.w), g1, acc);
    }
    if (e < end) {
      int2 q = cv[e];
      acc = fmaf(__int_as_float(q.y), GATH(q.x), acc);
    }
#undef GATH
    float a = xv + acc, m = xv * acc;
    amp[(size_t)row * 64 + f] = (unsigned)f2bf(a) | ((unsigned)f2bf(m) << 16);
  } else {
    // DIN == 32: half-wave edge-parallel
    int half = lane >> 5, f = lane & 31;
    float xv = (half == 0) ? xin[(size_t)row * 176 + f] : 0.0f;
#define GATH32(col) (BF ? bf2f(xh[(size_t)(unsigned)(col) * 64 + f]) \
                        : xin[(size_t)(unsigned)(col) * 176 + f])
    float acc = 0.0f;
    int e = beg;
    if ((e & 1) && e < end) {
      if (!half) {
        int2 q = cv[e];
        acc = fmaf(__int_as_float(q.y), GATH32(q.x), acc);
      }
      ++e;
    }
    for (; e + 8 <= end; e += 8) {
      iv4 a = *(const iv4*)(cv + e);      // edges e, e+1
      iv4 b = *(const iv4*)(cv + e + 2);  // e+2, e+3
      iv4 c = *(const iv4*)(cv + e + 4);
      iv4 d = *(const iv4*)(cv + e + 6);
      int c0 = half ? a.z : a.x;
      int c1 = half ? b.z : b.x;
      int c2 = half ? c.z : c.x;
      int c3 = half ? d.z : d.x;
      float v0 = __int_as_float(half ? a.w : a.y);
      float v1 = __int_as_float(half ? b.w : b.y);
      float v2 = __int_as_float(half ? c.w : c.y);
      float v3 = __int_as_float(half ? d.w : d.y);
      float g0 = GATH32(c0);
      float g1 = GATH32(c1);
      float g2 = GATH32(c2);
      float g3 = GATH32(c3);
      acc = fmaf(v0, g0, acc);
      acc = fmaf(v1, g1, acc);
      acc = fmaf(v2, g2, acc);
      acc = fmaf(v3, g3, acc);
    }
    for (; e + 2 <= end; e += 2) {
      iv4 a = *(const iv4*)(cv + e);
      int c0 = half ? a.z : a.x;
      float v0 = __int_as_float(half ? a.w : a.y);
      acc = fmaf(v0, GATH32(c0), acc);
    }
    if (e < end && !half) {
      int2 q = cv[e];
      acc = fmaf(__int_as_float(q.y), GATH32(q.x), acc);
    }
#undef GATH32
    acc += __shfl_xor(acc, 32);
    if (half == 0) {
      float a = xv + acc, m = xv * acc;
      amp[(size_t)row * 64 + f] = (unsigned)f2bf(a) | ((unsigned)f2bf(m) << 16);
    }
  }
}

// ---------------------------------------------------------------------------
// k_xf: MFMA transform. Block = 64 rows, 4 waves; wave w owns rows w*16..+16.
//   xn = leaky(A@W1 + b1) + leaky(M@W2 + b2)
// A/M and transposed W1/W2 staged in XOR-swizzled LDS.
// Writes f32 out (+ bf16 gather table xh for the next layer, if non-null).
// ---------------------------------------------------------------------------
template <int DIN, int DOUT>
__global__ void __launch_bounds__(256) k_xf(
    const unsigned* __restrict__ amp,
    const float* __restrict__ W1, const float* __restrict__ b1,
    const float* __restrict__ W2, const float* __restrict__ b2,
    float* __restrict__ outp, unsigned short* __restrict__ xh, int n) {
  constexpr int ROWB = DIN * 2;          // LDS row stride (bytes)
  constexpr int RMASK = (ROWB / 16) - 1; // swizzle mask
  constexpr int NTC = DOUT / 16;
  __shared__ unsigned short sA[64 * DIN];
  __shared__ unsigned short sM[64 * DIN];
  __shared__ unsigned short sW1[DOUT * DIN];
  __shared__ unsigned short sW2[DOUT * DIN];

  int row0 = blockIdx.x * 64;

  constexpr int PAIRS = DIN / 2;
  for (int i = threadIdx.x; i < 64 * PAIRS; i += 256) {
    int r = i / PAIRS, fp = (i - r * PAIRS) * 2;
    unsigned lo = 0, hi = 0;
    if (row0 + r < n) {
      uint2 q = *(const uint2*)(amp + (size_t)(row0 + r) * 64 + fp);
      lo = (q.x & 0xffffu) | ((q.y & 0xffffu) << 16);  // a pair
      hi = (q.x >> 16) | (q.y & 0xffff0000u);          // m pair
    }
    int boff = r * ROWB + ((fp * 2) ^ ((r & RMASK) << 4));
    *(unsigned*)((char*)sA + boff) = lo;
    *(unsigned*)((char*)sM + boff) = hi;
  }
  for (int i = threadIdx.x; i < DIN * DOUT; i += 256) {
    int k = i / DOUT, c = i - k * DOUT;
    int boff = c * ROWB + ((k * 2) ^ ((c & RMASK) << 4));
    *(unsigned short*)((char*)sW1 + boff) = f2bf(W1[i]);
    *(unsigned short*)((char*)sW2 + boff) = f2bf(W2[i]);
  }
  __syncthreads();

  int w = threadIdx.x >> 6, l = threadIdx.x & 63;
  int tr = w;

  f4 acc1[NTC], acc2[NTC];
#pragma unroll
  for (int tc = 0; tc < NTC; ++tc) {
    acc1[tc] = (f4){0.0f, 0.0f, 0.0f, 0.0f};
    acc2[tc] = (f4){0.0f, 0.0f, 0.0f, 0.0f};
  }

#pragma unroll
  for (int k0 = 0; k0 < DIN; k0 += 32) {
    int ra = tr * 16 + (l & 15);
    int inb = (k0 + (l >> 4) * 8) * 2;
    s8v af = *(const s8v*)((const char*)sA + ra * ROWB + (inb ^ ((ra & RMASK) << 4)));
    s8v mf = *(const s8v*)((const char*)sM + ra * ROWB + (inb ^ ((ra & RMASK) << 4)));
#pragma unroll
    for (int tc = 0; tc < NTC; ++tc) {
      int rc = tc * 16 + (l & 15);
      int wb = rc * ROWB + (inb ^ ((rc & RMASK) << 4));
      s8v w1 = *(const s8v*)((const char*)sW1 + wb);
      s8v w2 = *(const s8v*)((const char*)sW2 + wb);
      acc1[tc] = __builtin_amdgcn_mfma_f32_16x16x32_bf16(af, w1, acc1[tc], 0, 0, 0);
      acc2[tc] = __builtin_amdgcn_mfma_f32_16x16x32_bf16(mf, w2, acc2[tc], 0, 0, 0);
    }
  }

#pragma unroll
  for (int tc = 0; tc < NTC; ++tc) {
    int c = tc * 16 + (l & 15);
    float bb1 = b1[c], bb2 = b2[c];
#pragma unroll
    for (int j = 0; j < 4; ++j) {
      int r = tr * 16 + (l >> 4) * 4 + j;
      if (row0 + r < n) {
        float v1 = acc1[tc][j] + bb1;
        float v2 = acc2[tc][j] + bb2;
        float xn = LEAKY(v1) + LEAKY(v2);
        outp[(size_t)(row0 + r) * 176 + c] = xn;
        if (xh) xh[(size_t)(row0 + r) * 64 + c] = f2bf(xn);
      }
    }
  }
}

// ---------------------------------------------------------------------------
// k_norm: L2-normalize cols [64,128), [128,160), [160,176) in place.
// ---------------------------------------------------------------------------
__global__ void __launch_bounds__(256) k_norm(float* out, int n) {
  int row = (int)((blockIdx.x * (unsigned)blockDim.x + threadIdx.x) >> 6);
  int lane = threadIdx.x & 63;
  if (row >= n) return;
  float* r = out + (size_t)row * 176;
  float a = r[64 + lane];
  float b = (lane < 48) ? r[128 + lane] : 0.0f;
  float sa = a * a;
  float sb_ = (lane < 32) ? b * b : 0.0f;
  float sc = (lane >= 32 && lane < 48) ? b * b : 0.0f;
#pragma unroll
  for (int off = 32; off; off >>= 1) {
    sa += __shfl_xor(sa, off);
    sb_ += __shfl_xor(sb_, off);
    sc += __shfl_xor(sc, off);
  }
  float ia = 1.0f / fmaxf(sqrtf(sa), 1e-12f);
  float ib = 1.0f / fmaxf(sqrtf(sb_), 1e-12f);
  float ic = 1.0f / fmaxf(sqrtf(sc), 1e-12f);
  r[64 + lane] = a * ia;
  if (lane < 48) r[128 + lane] = b * ((lane < 32) ? ib : ic);
}

// ---------------------------------------------------------------------------
extern "C" void kernel_launch(void* const* d_in, const int* in_sizes, int n_in,
                              void* d_out, int out_size, void* d_ws, size_t ws_size,
                              hipStream_t stream) {
  const float* ego = (const float*)d_in[0];
  const int* erow = (const int*)d_in[1];
  const int* ecol = (const int*)d_in[2];
  const float* ev = (const float*)d_in[3];
  const int n = in_sizes[0] / 64;  // 160000
  const int E = in_sizes[1];       // 5120000
  const int nb = (n + RPB - 1) >> SH;

  float* out = (float*)d_out;  // [n, 176] f32

  // ws: bkt[E] (amp overlays) | cv[E] | rp[n+1] | meta | [xh if room]
  int2* bkt = (int2*)d_ws;
  int2* cv = bkt + E;
  int* rp = (int*)(cv + E);
  int* bcnt = rp + n + 1;
  int* boff = bcnt + NBMAX;
  int* bcur = boff + NBMAX + 1;
  unsigned short* xh = (unsigned short*)(bcur + NBMAX);
  unsigned* amp = (unsigned*)d_ws;  // overlays bkt (dead after k_bsort)

  size_t need_bf = (size_t)((char*)(xh + (size_t)n * 64) - (char*)d_ws);
  bool bf = ws_size >= need_bf;
  unsigned short* xhp = bf ? xh : nullptr;

  const int rblocks = (n + 3) / 4;   // k_gam: one wave per row
  const int xblocks = (n + 63) / 64; // k_xf: 64 rows per block

  k_init<<<2048, 256, 0, stream>>>(ego, out, xhp, n);
  hipMemsetAsync(bcnt, 0, NBMAX * sizeof(int), stream);
  k_hist<<<1024, 256, 0, stream>>>(erow, bcnt, E, nb);
  k_scanb<<<1, 64, 0, stream>>>(bcnt, boff, bcur, rp, nb, n, E);
  k_bucket<<<(E + CHUNK - 1) / CHUNK, 256, 0, stream>>>(erow, ecol, ev, bcur, bkt, E, nb);
  k_bsort<<<nb, 512, 0, stream>>>(boff, bkt, cv, rp, n);
  // bkt dead from here; amp takes its space

  const float* W1_0 = (const float*)d_in[4];
  const float* B1_0 = (const float*)d_in[5];
  const float* W2_0 = (const float*)d_in[6];
  const float* B2_0 = (const float*)d_in[7];
  const float* W1_1 = (const float*)d_in[8];
  const float* B1_1 = (const float*)d_in[9];
  const float* W2_1 = (const float*)d_in[10];
  const float* B2_1 = (const float*)d_in[11];
  const float* W1_2 = (const float*)d_in[12];
  const float* B1_2 = (const float*)d_in[13];
  const float* W2_2 = (const float*)d_in[14];
  const float* B2_2 = (const float*)d_in[15];

  if (bf) {
    k_gam<64, true><<<rblocks, 256, 0, stream>>>(rp, cv, xh, out, amp, n);
    k_xf<64, 64><<<xblocks, 256, 0, stream>>>(amp, W1_0, B1_0, W2_0, B2_0, out + 64, xh, n);
    k_gam<64, true><<<rblocks, 256, 0, stream>>>(rp, cv, xh, out + 64, amp, n);
    k_xf<64, 32><<<xblocks, 256, 0, stream>>>(amp, W1_1, B1_1, W2_1, B2_1, out + 128, xh, n);
    k_gam<32, true><<<rblocks, 256, 0, stream>>>(rp, cv, xh, out + 128, amp, n);
    k_xf<32, 16><<<xblocks, 256, 0, stream>>>(amp, W1_2, B1_2, W2_2, B2_2, out + 160, nullptr, n);
  } else {
    k_gam<64, false><<<rblocks, 256, 0, stream>>>(rp, cv, nullptr, out, amp, n);
    k_xf<64, 64><<<xblocks, 256, 0, stream>>>(amp, W1_0, B1_0, W2_0, B2_0, out + 64, nullptr, n);
    k_gam<64, false><<<rblocks, 256, 0, stream>>>(rp, cv, nullptr, out + 64, amp, n);
    k_xf<64, 32><<<xblocks, 256, 0, stream>>>(amp, W1_1, B1_1, W2_1, B2_1, out + 128, nullptr, n);
    k_gam<32, false><<<rblocks, 256, 0, stream>>>(rp, cv, nullptr, out + 128, amp, n);
    k_xf<32, 16><<<xblocks, 256, 0, stream>>>(amp, W1_2, B1_2, W2_2, B2_2, out + 160, nullptr, n);
  }

  k_norm<<<rblocks, 256, 0, stream>>>(out, n);
}

// Round 13
// 759.484 us; speedup vs baseline: 1.6852x; 1.0597x over previous
//
#include <hip/hip_runtime.h>
#include <hip/hip_bf16.h>

#define LEAKY(v) ((v) >= 0.0f ? (v) : 0.01f * (v))

typedef int iv4 __attribute__((ext_vector_type(4)));
typedef unsigned short us4 __attribute__((ext_vector_type(4)));
typedef short s8v __attribute__((ext_vector_type(8)));     // 8 bf16 (4 VGPRs)
typedef float f4 __attribute__((ext_vector_type(4)));      // MFMA acc
typedef float fv8 __attribute__((ext_vector_type(8)));     // 8 f32
typedef unsigned uv8 __attribute__((ext_vector_type(8)));  // 8 u32

constexpr int SH = 9;        // rows per bucket = 512
constexpr int RPB = 1 << SH; // 512
constexpr int NBMAX = 320;   // max buckets (n <= 163840)
constexpr int CHUNK = 6144;  // edges per phase-1 block

__device__ __forceinline__ unsigned short f2bf(float v) {
  unsigned u = __float_as_uint(v);
  return (unsigned short)((u + 0x7fffu + ((u >> 16) & 1u)) >> 16);  // RNE
}
__device__ __forceinline__ float bf2f(unsigned short h) {
  return __uint_as_float((unsigned)h << 16);
}

// ---------------------------------------------------------------------------
// k_init: ego -> out cols [0,64); optionally also bf16 gather table xh.
// ---------------------------------------------------------------------------
__global__ void k_init(const float* __restrict__ ego, float* __restrict__ out,
                       unsigned short* __restrict__ xh, int n) {
  int tid = blockIdx.x * blockDim.x + threadIdx.x;
  int total = n * 16;
  int stride = gridDim.x * blockDim.x;
  for (int t = tid; t < total; t += stride) {
    int r = t >> 4, c = (t & 15) * 4;
    float4 v = *(const float4*)(ego + (size_t)r * 64 + c);
    *(float4*)(out + (size_t)r * 176 + c) = v;
    if (xh) {
      us4 h;
      h.x = f2bf(v.x); h.y = f2bf(v.y); h.z = f2bf(v.z); h.w = f2bf(v.w);
      *(us4*)(xh + (size_t)r * 64 + c) = h;
    }
  }
}

// ---------------------------------------------------------------------------
// Sort pipeline (proven round 9): hist -> scanb -> bucket -> bsort
// ---------------------------------------------------------------------------
__global__ void __launch_bounds__(256) k_hist(const int* __restrict__ erow,
                                              int* __restrict__ bcnt, int E, int nb) {
  __shared__ int h[NBMAX];
  for (int i = threadIdx.x; i < NBMAX; i += 256) h[i] = 0;
  __syncthreads();
  int tid = blockIdx.x * blockDim.x + threadIdx.x;
  int stride = gridDim.x * blockDim.x;
  for (int e = tid; e < E; e += stride) atomicAdd(&h[erow[e] >> SH], 1);
  __syncthreads();
  for (int b = threadIdx.x; b < nb; b += 256)
    if (h[b]) atomicAdd(&bcnt[b], h[b]);
}

__global__ void k_scanb(const int* __restrict__ bcnt, int* __restrict__ boff,
                        int* __restrict__ bcur, int* __restrict__ rp,
                        int nb, int n, int E) {
  int l = threadIdx.x;  // 64 threads
  constexpr int PB = NBMAX / 64;
  int local[PB];
  int s = 0;
  int base = l * PB;
  for (int j = 0; j < PB; ++j) {
    int b = base + j;
    int c = (b < nb) ? bcnt[b] : 0;
    local[j] = c;
    s += c;
  }
  int incl = s;
  for (int d = 1; d < 64; d <<= 1) {
    int v = __shfl_up(incl, d);
    if (l >= d) incl += v;
  }
  int ex = incl - s;
  for (int j = 0; j < PB; ++j) {
    int b = base + j;
    if (b <= nb) { boff[b] = ex; bcur[b] = ex; }
    ex += local[j];
  }
  if (l == 63) boff[nb] = incl;
  if (l == 0) rp[n] = E;
}

__global__ void __launch_bounds__(256) k_bucket(
    const int* __restrict__ erow, const int* __restrict__ ecol,
    const float* __restrict__ ev, int* __restrict__ bcur,
    int2* __restrict__ bkt, int E, int nb) {
  __shared__ int hist[NBMAX];
  __shared__ int excl[NBMAX + 1];
  __shared__ int curl[NBMAX];
  __shared__ int gbase[NBMAX];
  __shared__ int2 skv[CHUNK];
  int base = blockIdx.x * CHUNK;
  int cnt = min(CHUNK, E - base);

  for (int i = threadIdx.x; i < NBMAX; i += 256) hist[i] = 0;
  __syncthreads();
  for (int i = threadIdx.x; i < cnt; i += 256)
    atomicAdd(&hist[erow[base + i] >> SH], 1);
  __syncthreads();

  if (threadIdx.x < 64) {
    int l = threadIdx.x;
    constexpr int PB = NBMAX / 64;
    int lsum[PB];
    int s = 0;
    for (int j = 0; j < PB; ++j) { lsum[j] = hist[l * PB + j]; s += lsum[j]; }
    int incl = s;
    for (int d = 1; d < 64; d <<= 1) {
      int v = __shfl_up(incl, d);
      if (l >= d) incl += v;
    }
    int ex = incl - s;
    for (int j = 0; j < PB; ++j) { excl[l * PB + j] = ex; ex += lsum[j]; }
    if (l == 63) excl[NBMAX] = incl;
  }
  __syncthreads();

  for (int b = threadIdx.x; b < nb; b += 256) {
    curl[b] = 0;
    int c = hist[b];
    if (c) gbase[b] = atomicAdd(&bcur[b], c);
  }
  __syncthreads();

  for (int i = threadIdx.x; i < cnt; i += 256) {
    int r = erow[base + i];
    int b = r >> SH;
    int lr = r & (RPB - 1);
    int slot = excl[b] + atomicAdd(&curl[b], 1);
    int2 p;
    p.x = (lr << 18) | ecol[base + i];
    p.y = __float_as_int(ev[base + i]);
    skv[slot] = p;
  }
  __syncthreads();

  for (int s = threadIdx.x; s < cnt; s += 256) {
    int lo = 0, hi = nb;
    while (hi - lo > 1) {
      int mid = (lo + hi) >> 1;
      if (excl[mid] <= s) lo = mid; else hi = mid;
    }
    bkt[gbase[lo] + (s - excl[lo])] = skv[s];
  }
}

__global__ void __launch_bounds__(512) k_bsort(
    const int* __restrict__ boff, const int2* __restrict__ bkt,
    int2* __restrict__ cv, int* __restrict__ rp, int n) {
  __shared__ int cnt[RPB];
  __shared__ int sc[RPB];
  __shared__ int exs[RPB];
  __shared__ int cur[RPB];
  int b = blockIdx.x;
  int off = boff[b];
  int m = boff[b + 1] - off;
  int t = threadIdx.x;

  cnt[t] = 0;
  __syncthreads();
  for (int i = t; i < m; i += 512) atomicAdd(&cnt[bkt[off + i].x >> 18], 1);
  __syncthreads();
  sc[t] = cnt[t];
  __syncthreads();
  for (int o = 1; o < RPB; o <<= 1) {
    int v = (t >= o) ? sc[t - o] : 0;
    __syncthreads();
    sc[t] += v;
    __syncthreads();
  }
  int ex = sc[t] - cnt[t];
  exs[t] = ex;
  cur[t] = 0;
  int row = (b << SH) + t;
  if (row < n) rp[row] = off + ex;
  __syncthreads();
  for (int i = t; i < m; i += 512) {
    int2 p = bkt[off + i];
    int lr = p.x >> 18;
    int pos = exs[lr] + atomicAdd(&cur[lr], 1);
    int2 q;
    q.x = p.x & 0x3FFFF;
    q.y = p.y;
    cv[off + pos] = q;
  }
}

// ---------------------------------------------------------------------------
// k_gam: gather-only SpMM, CHUNKED: each edge handled by LPE=DIN/8 lanes,
// each lane gathers a 16B chunk (8 bf16) of xh[col] -> 1 address per 16B
// (8x fewer addresses + 8x less addr-VALU than per-lane-scalar gather).
// DIN=64: 8 edges/iter; DIN=32: 16 edges/iter. cv prefetched 1-deep.
// End: shfl_xor reduce over edge slots; lanes<LPE write packed a/m (32B).
// BF=false fallback: proven scalar path (never exercised when ws >= 104MB).
// ---------------------------------------------------------------------------
template <int DIN, bool BF>
__global__ void __launch_bounds__(256, 8) k_gam(
    const int* __restrict__ rp, const int2* __restrict__ cv,
    const unsigned short* __restrict__ xh, const float* __restrict__ xin,
    unsigned* __restrict__ amp, int n) {
  int row = (int)((blockIdx.x * (unsigned)blockDim.x + threadIdx.x) >> 6);
  int lane = threadIdx.x & 63;
  if (row >= n) return;

  int beg = rp[row], end = rp[row + 1];

  if constexpr (BF) {
    constexpr int LPE = DIN / 8;   // lanes per edge (8 or 4)
    constexpr int EPI = 64 / LPE;  // edges per iteration (8 or 16)
    int eg = lane / LPE;           // edge slot
    int ch = lane % LPE;           // 16B chunk index

    float acc[8];
#pragma unroll
    for (int j = 0; j < 8; ++j) acc[j] = 0.0f;

    if (beg < end) {
      int2 q = cv[min(beg + eg, end - 1)];
      for (int e = beg; e < end; e += EPI) {
        int2 qn = cv[min(e + EPI + eg, end - 1)];  // prefetch next iter
        float val = (e + eg < end) ? __int_as_float(q.y) : 0.0f;
        s8v xr = *(const s8v*)(xh + (size_t)(unsigned)q.x * 64 + ch * 8);
#pragma unroll
        for (int j = 0; j < 4; ++j) {
          unsigned d = ((const unsigned*)&xr)[j];
          acc[2 * j] = fmaf(val, __uint_as_float(d << 16), acc[2 * j]);
          acc[2 * j + 1] = fmaf(val, __uint_as_float(d & 0xffff0000u), acc[2 * j + 1]);
        }
        q = qn;
      }
    }

    // reduce across edge slots (lanes sharing chunk index)
#pragma unroll
    for (int off = LPE; off < 64; off <<= 1) {
#pragma unroll
      for (int j = 0; j < 8; ++j) acc[j] += __shfl_xor(acc[j], off);
    }

    if (lane < LPE) {
      fv8 xv = *(const fv8*)(xin + (size_t)row * 176 + lane * 8);
      uv8 w;
#pragma unroll
      for (int j = 0; j < 8; ++j) {
        float a = xv[j] + acc[j];
        float m = xv[j] * acc[j];
        w[j] = (unsigned)f2bf(a) | ((unsigned)f2bf(m) << 16);
      }
      *(uv8*)(amp + (size_t)row * 64 + lane * 8) = w;
    }
  } else {
    // fallback: per-lane scalar f32 gather (proven round-9 path)
    int f = lane & (DIN - 1);
    float xv = (lane < DIN) ? xin[(size_t)row * 176 + lane] : 0.0f;
    float acc = 0.0f;
    int e = beg;
    if ((e & 1) && e < end) {
      int2 q = cv[e];
      acc = fmaf(__int_as_float(q.y), xin[(size_t)(unsigned)q.x * 176 + f], acc);
      ++e;
    }
    for (; e + 2 <= end; e += 2) {
      iv4 a = *(const iv4*)(cv + e);
      float g0 = xin[(size_t)(unsigned)a.x * 176 + f];
      float g1 = xin[(size_t)(unsigned)a.z * 176 + f];
      acc = fmaf(__int_as_float(a.y), g0, acc);
      acc = fmaf(__int_as_float(a.w), g1, acc);
    }
    if (e < end) {
      int2 q = cv[e];
      acc = fmaf(__int_as_float(q.y), xin[(size_t)(unsigned)q.x * 176 + f], acc);
    }
    if (lane < DIN) {
      float a = xv + acc, m = xv * acc;
      amp[(size_t)row * 64 + lane] = (unsigned)f2bf(a) | ((unsigned)f2bf(m) << 16);
    }
  }
}

// ---------------------------------------------------------------------------
// k_xf: MFMA transform. Block = 64 rows, 4 waves; wave w owns rows w*16..+16.
//   xn = leaky(A@W1 + b1) + leaky(M@W2 + b2)
// A/M and transposed W1/W2 staged in XOR-swizzled LDS.
// Writes f32 out (+ bf16 gather table xh for the next layer, if non-null).
// ---------------------------------------------------------------------------
template <int DIN, int DOUT>
__global__ void __launch_bounds__(256) k_xf(
    const unsigned* __restrict__ amp,
    const float* __restrict__ W1, const float* __restrict__ b1,
    const float* __restrict__ W2, const float* __restrict__ b2,
    float* __restrict__ outp, unsigned short* __restrict__ xh, int n) {
  constexpr int ROWB = DIN * 2;          // LDS row stride (bytes)
  constexpr int RMASK = (ROWB / 16) - 1; // swizzle mask
  constexpr int NTC = DOUT / 16;
  __shared__ unsigned short sA[64 * DIN];
  __shared__ unsigned short sM[64 * DIN];
  __shared__ unsigned short sW1[DOUT * DIN];
  __shared__ unsigned short sW2[DOUT * DIN];

  int row0 = blockIdx.x * 64;

  constexpr int PAIRS = DIN / 2;
  for (int i = threadIdx.x; i < 64 * PAIRS; i += 256) {
    int r = i / PAIRS, fp = (i - r * PAIRS) * 2;
    unsigned lo = 0, hi = 0;
    if (row0 + r < n) {
      uint2 q = *(const uint2*)(amp + (size_t)(row0 + r) * 64 + fp);
      lo = (q.x & 0xffffu) | ((q.y & 0xffffu) << 16);  // a pair
      hi = (q.x >> 16) | (q.y & 0xffff0000u);          // m pair
    }
    int boff = r * ROWB + ((fp * 2) ^ ((r & RMASK) << 4));
    *(unsigned*)((char*)sA + boff) = lo;
    *(unsigned*)((char*)sM + boff) = hi;
  }
  for (int i = threadIdx.x; i < DIN * DOUT; i += 256) {
    int k = i / DOUT, c = i - k * DOUT;
    int boff = c * ROWB + ((k * 2) ^ ((c & RMASK) << 4));
    *(unsigned short*)((char*)sW1 + boff) = f2bf(W1[i]);
    *(unsigned short*)((char*)sW2 + boff) = f2bf(W2[i]);
  }
  __syncthreads();

  int w = threadIdx.x >> 6, l = threadIdx.x & 63;
  int tr = w;

  f4 acc1[NTC], acc2[NTC];
#pragma unroll
  for (int tc = 0; tc < NTC; ++tc) {
    acc1[tc] = (f4){0.0f, 0.0f, 0.0f, 0.0f};
    acc2[tc] = (f4){0.0f, 0.0f, 0.0f, 0.0f};
  }

#pragma unroll
  for (int k0 = 0; k0 < DIN; k0 += 32) {
    int ra = tr * 16 + (l & 15);
    int inb = (k0 + (l >> 4) * 8) * 2;
    s8v af = *(const s8v*)((const char*)sA + ra * ROWB + (inb ^ ((ra & RMASK) << 4)));
    s8v mf = *(const s8v*)((const char*)sM + ra * ROWB + (inb ^ ((ra & RMASK) << 4)));
#pragma unroll
    for (int tc = 0; tc < NTC; ++tc) {
      int rc = tc * 16 + (l & 15);
      int wb = rc * ROWB + (inb ^ ((rc & RMASK) << 4));
      s8v w1 = *(const s8v*)((const char*)sW1 + wb);
      s8v w2 = *(const s8v*)((const char*)sW2 + wb);
      acc1[tc] = __builtin_amdgcn_mfma_f32_16x16x32_bf16(af, w1, acc1[tc], 0, 0, 0);
      acc2[tc] = __builtin_amdgcn_mfma_f32_16x16x32_bf16(mf, w2, acc2[tc], 0, 0, 0);
    }
  }

#pragma unroll
  for (int tc = 0; tc < NTC; ++tc) {
    int c = tc * 16 + (l & 15);
    float bb1 = b1[c], bb2 = b2[c];
#pragma unroll
    for (int j = 0; j < 4; ++j) {
      int r = tr * 16 + (l >> 4) * 4 + j;
      if (row0 + r < n) {
        float v1 = acc1[tc][j] + bb1;
        float v2 = acc2[tc][j] + bb2;
        float xn = LEAKY(v1) + LEAKY(v2);
        outp[(size_t)(row0 + r) * 176 + c] = xn;
        if (xh) xh[(size_t)(row0 + r) * 64 + c] = f2bf(xn);
      }
    }
  }
}

// ---------------------------------------------------------------------------
// k_norm: L2-normalize cols [64,128), [128,160), [160,176) in place.
// ---------------------------------------------------------------------------
__global__ void __launch_bounds__(256) k_norm(float* out, int n) {
  int row = (int)((blockIdx.x * (unsigned)blockDim.x + threadIdx.x) >> 6);
  int lane = threadIdx.x & 63;
  if (row >= n) return;
  float* r = out + (size_t)row * 176;
  float a = r[64 + lane];
  float b = (lane < 48) ? r[128 + lane] : 0.0f;
  float sa = a * a;
  float sb_ = (lane < 32) ? b * b : 0.0f;
  float sc = (lane >= 32 && lane < 48) ? b * b : 0.0f;
#pragma unroll
  for (int off = 32; off; off >>= 1) {
    sa += __shfl_xor(sa, off);
    sb_ += __shfl_xor(sb_, off);
    sc += __shfl_xor(sc, off);
  }
  float ia = 1.0f / fmaxf(sqrtf(sa), 1e-12f);
  float ib = 1.0f / fmaxf(sqrtf(sb_), 1e-12f);
  float ic = 1.0f / fmaxf(sqrtf(sc), 1e-12f);
  r[64 + lane] = a * ia;
  if (lane < 48) r[128 + lane] = b * ((lane < 32) ? ib : ic);
}

// ---------------------------------------------------------------------------
extern "C" void kernel_launch(void* const* d_in, const int* in_sizes, int n_in,
                              void* d_out, int out_size, void* d_ws, size_t ws_size,
                              hipStream_t stream) {
  const float* ego = (const float*)d_in[0];
  const int* erow = (const int*)d_in[1];
  const int* ecol = (const int*)d_in[2];
  const float* ev = (const float*)d_in[3];
  const int n = in_sizes[0] / 64;  // 160000
  const int E = in_sizes[1];       // 5120000
  const int nb = (n + RPB - 1) >> SH;

  float* out = (float*)d_out;  // [n, 176] f32

  // ws: bkt[E] (amp overlays) | cv[E] | rp[n+1] | meta | [xh if room]
  int2* bkt = (int2*)d_ws;
  int2* cv = bkt + E;
  int* rp = (int*)(cv + E);
  int* bcnt = rp + n + 1;
  int* boff = bcnt + NBMAX;
  int* bcur = boff + NBMAX + 1;
  unsigned short* xh = (unsigned short*)(bcur + NBMAX);
  unsigned* amp = (unsigned*)d_ws;  // overlays bkt (dead after k_bsort)

  size_t need_bf = (size_t)((char*)(xh + (size_t)n * 64) - (char*)d_ws);
  bool bf = ws_size >= need_bf;
  unsigned short* xhp = bf ? xh : nullptr;

  const int rblocks = (n + 3) / 4;   // k_gam: one wave per row
  const int xblocks = (n + 63) / 64; // k_xf: 64 rows per block

  k_init<<<2048, 256, 0, stream>>>(ego, out, xhp, n);
  hipMemsetAsync(bcnt, 0, NBMAX * sizeof(int), stream);
  k_hist<<<1024, 256, 0, stream>>>(erow, bcnt, E, nb);
  k_scanb<<<1, 64, 0, stream>>>(bcnt, boff, bcur, rp, nb, n, E);
  k_bucket<<<(E + CHUNK - 1) / CHUNK, 256, 0, stream>>>(erow, ecol, ev, bcur, bkt, E, nb);
  k_bsort<<<nb, 512, 0, stream>>>(boff, bkt, cv, rp, n);
  // bkt dead from here; amp takes its space

  const float* W1_0 = (const float*)d_in[4];
  const float* B1_0 = (const float*)d_in[5];
  const float* W2_0 = (const float*)d_in[6];
  const float* B2_0 = (const float*)d_in[7];
  const float* W1_1 = (const float*)d_in[8];
  const float* B1_1 = (const float*)d_in[9];
  const float* W2_1 = (const float*)d_in[10];
  const float* B2_1 = (const float*)d_in[11];
  const float* W1_2 = (const float*)d_in[12];
  const float* B1_2 = (const float*)d_in[13];
  const float* W2_2 = (const float*)d_in[14];
  const float* B2_2 = (const float*)d_in[15];

  if (bf) {
    k_gam<64, true><<<rblocks, 256, 0, stream>>>(rp, cv, xh, out, amp, n);
    k_xf<64, 64><<<xblocks, 256, 0, stream>>>(amp, W1_0, B1_0, W2_0, B2_0, out + 64, xh, n);
    k_gam<64, true><<<rblocks, 256, 0, stream>>>(rp, cv, xh, out + 64, amp, n);
    k_xf<64, 32><<<xblocks, 256, 0, stream>>>(amp, W1_1, B1_1, W2_1, B2_1, out + 128, xh, n);
    k_gam<32, true><<<rblocks, 256, 0, stream>>>(rp, cv, xh, out + 128, amp, n);
    k_xf<32, 16><<<xblocks, 256, 0, stream>>>(amp, W1_2, B1_2, W2_2, B2_2, out + 160, nullptr, n);
  } else {
    k_gam<64, false><<<rblocks, 256, 0, stream>>>(rp, cv, nullptr, out, amp, n);
    k_xf<64, 64><<<xblocks, 256, 0, stream>>>(amp, W1_0, B1_0, W2_0, B2_0, out + 64, nullptr, n);
    k_gam<64, false><<<rblocks, 256, 0, stream>>>(rp, cv, nullptr, out + 64, amp, n);
    k_xf<64, 32><<<xblocks, 256, 0, stream>>>(amp, W1_1, B1_1, W2_1, B2_1, out + 128, nullptr, n);
    k_gam<32, false><<<rblocks, 256, 0, stream>>>(rp, cv, nullptr, out + 128, amp, n);
    k_xf<32, 16><<<xblocks, 256, 0, stream>>>(amp, W1_2, B1_2, W2_2, B2_2, out + 160, nullptr, n);
  }

  k_norm<<<rblocks, 256, 0, stream>>>(out, n);
}